// Round 1
// baseline (2725.504 us; speedup 1.0000x reference)
//
#include <hip/hip_runtime.h>
#include <hip/hip_bf16.h>

#define PI_F 3.14159265358979323846f
#define NFFT 2048
#define LOG2N 11

// ---------------------------------------------------------------------------
// Kernel A: projection GEMM, output TRANSPOSED to [B, D=512, T=2048]
// X: [B*T, 512] row-major, W: [512,512], bias: [512]
// YT[b][n][t] = sum_c X[b*2048+t][c] * W[c][n] + bias[n]
// Tiling: BM=128 (t), BN=64 (n), BK=32. 256 threads, 8x4 microtile.
// ---------------------------------------------------------------------------
__global__ __launch_bounds__(256) void proj_gemm_T(
    const float* __restrict__ X, const float* __restrict__ W,
    const float* __restrict__ bias, float* __restrict__ YT) {
  __shared__ float As[32][128];  // [k][m]
  __shared__ float Bs[32][64];   // [k][n]
  const int tid = threadIdx.x;
  const int n0 = blockIdx.x * 64;
  const int m0 = blockIdx.y * 128;
  const int tm = tid & 15;   // m-subtile (8 m each) -> lanes adjacent in m (=t)
  const int tn = tid >> 4;   // n-subtile (4 n each)

  float acc[4][8];
#pragma unroll
  for (int i = 0; i < 4; i++)
#pragma unroll
    for (int j = 0; j < 8; j++) acc[i][j] = 0.f;

  const int a_k4 = (tid & 7) * 4;  // k offset within 32 (float4)
  const int a_m  = tid >> 3;       // 0..31, +32 per pass
  const int b_n4 = (tid & 15) * 4;
  const int b_k  = tid >> 4;       // 0..15, +16 per pass

  for (int k0 = 0; k0 < 512; k0 += 32) {
#pragma unroll
    for (int r = 0; r < 4; r++) {
      int m = a_m + r * 32;
      float4 v = *(const float4*)&X[(size_t)(m0 + m) * 512 + k0 + a_k4];
      As[a_k4 + 0][m] = v.x;
      As[a_k4 + 1][m] = v.y;
      As[a_k4 + 2][m] = v.z;
      As[a_k4 + 3][m] = v.w;
    }
#pragma unroll
    for (int r = 0; r < 2; r++) {
      int kk = b_k + r * 16;
      *(float4*)&Bs[kk][b_n4] =
          *(const float4*)&W[(size_t)(k0 + kk) * 512 + n0 + b_n4];
    }
    __syncthreads();
#pragma unroll
    for (int k = 0; k < 32; k++) {
      float a[8], bb[4];
      *(float4*)&a[0] = *(const float4*)&As[k][tm * 8];
      *(float4*)&a[4] = *(const float4*)&As[k][tm * 8 + 4];
      *(float4*)&bb[0] = *(const float4*)&Bs[k][tn * 4];
#pragma unroll
      for (int ni = 0; ni < 4; ni++)
#pragma unroll
        for (int mi = 0; mi < 8; mi++) acc[ni][mi] += a[mi] * bb[ni];
    }
    __syncthreads();
  }

  // store transposed: YT[b][n][t], m = m0 + tm*8 + mi, n = n0 + tn*4 + ni
  const int b = m0 >> 11;        // 128 | 2048 so tile is within one batch
  const int tbase = (m0 & 2047) + tm * 8;
  const float4 bs4 = *(const float4*)&bias[n0 + tn * 4];
  const float bsv[4] = {bs4.x, bs4.y, bs4.z, bs4.w};
#pragma unroll
  for (int ni = 0; ni < 4; ni++) {
    int n = n0 + tn * 4 + ni;
    float bsc = bsv[ni];
    float4 v0 = make_float4(acc[ni][0] + bsc, acc[ni][1] + bsc,
                            acc[ni][2] + bsc, acc[ni][3] + bsc);
    float4 v1 = make_float4(acc[ni][4] + bsc, acc[ni][5] + bsc,
                            acc[ni][6] + bsc, acc[ni][7] + bsc);
    size_t off = ((size_t)b * 512 + n) * 2048 + tbase;
    *(float4*)&YT[off] = v0;
    *(float4*)&YT[off + 4] = v1;
  }
}

// ---------------------------------------------------------------------------
// FFT correlate: per (b, feature-pair) block. qT,kT: [B,512,2048].
// attn written IN PLACE over qT rows.
// ---------------------------------------------------------------------------
__device__ inline void fft2048_dif(float2* Z, int tid) {
  // DIF, natural in -> bit-reversed out. 256 threads x 4 butterflies/stage.
  for (int s = 0; s < LOG2N; s++) {
    int half = NFFT >> (s + 1);
    float angScale = -PI_F / (float)half;
#pragma unroll
    for (int r = 0; r < 4; r++) {
      int p = tid + (r << 8);
      int j = p & (half - 1);
      int i0 = (p << 1) - j;
      int i1 = i0 + half;
      float2 u = Z[i0], v = Z[i1];
      float sx = u.x + v.x, sy = u.y + v.y;
      float dx = u.x - v.x, dy = u.y - v.y;
      float sn, cs;
      __sincosf(angScale * (float)j, &sn, &cs);
      Z[i0] = make_float2(sx, sy);
      Z[i1] = make_float2(dx * cs - dy * sn, dx * sn + dy * cs);
    }
    __syncthreads();
  }
}

__device__ inline void bitrev2048(float2* Z, int tid) {
#pragma unroll
  for (int r = 0; r < 8; r++) {
    int i = tid + (r << 8);
    int rv = (int)(__brev((unsigned)i) >> 21);
    if (i < rv) {
      float2 a = Z[i];
      Z[i] = Z[rv];
      Z[rv] = a;
    }
  }
  __syncthreads();
}

__global__ __launch_bounds__(256) void fft_correlate(
    float* __restrict__ qT, const float* __restrict__ kT) {
  __shared__ float2 Z[NFFT];
  __shared__ float2 Wb[NFFT];
  const int b = blockIdx.x;
  const int d0 = blockIdx.y * 2;
  const int tid = threadIdx.x;
  const size_t base = ((size_t)b * 512 + d0) * 2048;

#pragma unroll
  for (int r = 0; r < 8; r++) {
    int t = tid + (r << 8);
    Z[t] = make_float2(qT[base + t], qT[base + 2048 + t]);
    Wb[t] = make_float2(kT[base + t], kT[base + 2048 + t]);
  }
  __syncthreads();

  fft2048_dif(Z, tid);
  bitrev2048(Z, tid);
  fft2048_dif(Wb, tid);
  bitrev2048(Wb, tid);

  // pointwise: PF[f] = 1/4 [ (Zf + conj(Zn))(conj(Wf) + Wn)
  //                         + i (Zf - conj(Zn))(conj(Wf) - Wn) ],  n = (N-f)%N
  // store conj(PF) (prepares inverse FFT via conj-FFT-conj)
  float2 res[8];
#pragma unroll
  for (int r = 0; r < 8; r++) {
    int f = tid + (r << 8);
    int fn = (NFFT - f) & (NFFT - 1);
    float2 Zf = Z[f], Zn = Z[fn], Wf = Wb[f], Wn = Wb[fn];
    float A1x = Zf.x + Zn.x, A1y = Zf.y - Zn.y;
    float B1x = Wf.x + Wn.x, B1y = Wn.y - Wf.y;
    float A2x = Zf.x - Zn.x, A2y = Zf.y + Zn.y;
    float B2x = Wf.x - Wn.x, B2y = -Wf.y - Wn.y;
    float p1x = A1x * B1x - A1y * B1y;
    float p1y = A1x * B1y + A1y * B1x;
    float p2x = A2x * B2x - A2y * B2y;
    float p2y = A2x * B2y + A2y * B2x;
    float pfx = 0.25f * (p1x - p2y);
    float pfy = 0.25f * (p1y + p2x);
    res[r] = make_float2(pfx, -pfy);  // conj(PF)
  }
  __syncthreads();
#pragma unroll
  for (int r = 0; r < 8; r++) Z[tid + (r << 8)] = res[r];
  __syncthreads();

  fft2048_dif(Z, tid);
  bitrev2048(Z, tid);

  const float scale = 1.0f / (float)NFFT;
#pragma unroll
  for (int r = 0; r < 8; r++) {
    int t = tid + (r << 8);
    float2 z = Z[t];
    qT[base + t] = z.x * scale;         // attn for feature d0
    qT[base + 2048 + t] = -z.y * scale; // attn for feature d0+1
  }
}

// ---------------------------------------------------------------------------
// Column stats over d: mean (for top-k) + online softmax (max, expsum)
// attnT: [B,512,2048]
// ---------------------------------------------------------------------------
__global__ __launch_bounds__(256) void colstats_kernel(
    const float* __restrict__ attnT, float* __restrict__ mean,
    float2* __restrict__ stats) {
  const int b = blockIdx.x;
  const int t = blockIdx.y * 256 + threadIdx.x;
  const size_t base = (size_t)b * 512 * 2048 + t;
  float sum = 0.f, m = -1e30f, s = 0.f;
  for (int d = 0; d < 512; d++) {
    float a = attnT[base + (size_t)d * 2048];
    sum += a;
    float mn = fmaxf(m, a);
    s = s * __expf(m - mn) + __expf(a - mn);
    m = mn;
  }
  mean[b * 2048 + t] = sum * (1.f / 512.f);
  stats[b * 2048 + t] = make_float2(m, s);
}

// ---------------------------------------------------------------------------
// Top-15 per batch (iterative argmax, lowest-index tie-break)
// ---------------------------------------------------------------------------
__global__ __launch_bounds__(256) void topk_kernel(
    const float* __restrict__ mean, int* __restrict__ delays) {
  __shared__ float vals[2048];
  __shared__ float sv[256];
  __shared__ int si[256];
  const int b = blockIdx.x, tid = threadIdx.x;
#pragma unroll
  for (int r = 0; r < 8; r++)
    vals[tid + (r << 8)] = mean[b * 2048 + tid + (r << 8)];
  __syncthreads();
  for (int k = 0; k < 15; k++) {
    float bv = -1e30f;
    int bi = 1 << 30;
#pragma unroll
    for (int r = 0; r < 8; r++) {
      int i = (r << 8) + tid;
      float v = vals[i];
      if (v > bv || (v == bv && i < bi)) { bv = v; bi = i; }
    }
    sv[tid] = bv;
    si[tid] = bi;
    __syncthreads();
    for (int off = 128; off > 0; off >>= 1) {
      if (tid < off) {
        float v2 = sv[tid + off];
        int i2 = si[tid + off];
        if (v2 > sv[tid] || (v2 == sv[tid] && i2 < si[tid])) {
          sv[tid] = v2;
          si[tid] = i2;
        }
      }
      __syncthreads();
    }
    if (tid == 0) {
      delays[b * 15 + k] = si[0];
      vals[si[0]] = -1e30f;
    }
    __syncthreads();
  }
}

// ---------------------------------------------------------------------------
// Context: ctxT[b][d][t] = softmax_d(attn) * sum_k v[b][d][(t - delay_k) % T]
// ---------------------------------------------------------------------------
__global__ __launch_bounds__(256) void ctx_kernel(
    const float* __restrict__ attnT, const float* __restrict__ vT,
    const float2* __restrict__ stats, const int* __restrict__ delays,
    float* __restrict__ ctxT) {
  const int b = blockIdx.x;
  const int d0 = blockIdx.y * 32;
  const int t = blockIdx.z * 256 + threadIdx.x;
  __shared__ int dly[15];
  if (threadIdx.x < 15) dly[threadIdx.x] = delays[b * 15 + threadIdx.x];
  __syncthreads();
  float2 st = stats[b * 2048 + t];
  const float m = st.x;
  const float inv = 1.f / st.y;
  const size_t base = (size_t)b * 512 * 2048;
  for (int d = d0; d < d0 + 32; d++) {
    const float* vr = vT + base + (size_t)d * 2048;
    float rolled = 0.f;
#pragma unroll
    for (int k = 0; k < 15; k++) rolled += vr[(t - dly[k]) & 2047];
    float a = attnT[base + (size_t)d * 2048 + t];
    ctxT[base + (size_t)d * 2048 + t] = __expf(a - m) * inv * rolled;
  }
}

// ---------------------------------------------------------------------------
// Output GEMM: Y[b*2048+t][n] = sum_d ctxT[b][d][t] * Wo[d][n] + bo[n]
// A is K-major (contiguous in m=t) -> direct coalesced LDS staging.
// ---------------------------------------------------------------------------
__global__ __launch_bounds__(256) void out_gemm(
    const float* __restrict__ AT, const float* __restrict__ W,
    const float* __restrict__ bias, float* __restrict__ Y) {
  __shared__ float As[32][128];  // [k][m]
  __shared__ float Bs[32][64];   // [k][n]
  const int tid = threadIdx.x;
  const int n0 = blockIdx.x * 64;
  const int m0 = blockIdx.y * 128;
  const int b = m0 >> 11;
  const int t0 = m0 & 2047;
  const int tn = tid & 15;  // n-subtile -> lanes adjacent in n for store
  const int tm = tid >> 4;  // m-subtile (8 m each)

  float acc[8][4];
#pragma unroll
  for (int i = 0; i < 8; i++)
#pragma unroll
    for (int j = 0; j < 4; j++) acc[i][j] = 0.f;

  const int a_m4 = (tid & 31) * 4;
  const int a_k  = tid >> 5;  // 0..7, +8 per pass
  const int b_n4 = (tid & 15) * 4;
  const int b_k  = tid >> 4;  // 0..15, +16 per pass

  const float* Abase = AT + (size_t)b * 512 * 2048 + t0;
  for (int k0 = 0; k0 < 512; k0 += 32) {
#pragma unroll
    for (int r = 0; r < 4; r++) {
      int kk = a_k + r * 8;
      *(float4*)&As[kk][a_m4] =
          *(const float4*)&Abase[(size_t)(k0 + kk) * 2048 + a_m4];
    }
#pragma unroll
    for (int r = 0; r < 2; r++) {
      int kk = b_k + r * 16;
      *(float4*)&Bs[kk][b_n4] =
          *(const float4*)&W[(size_t)(k0 + kk) * 512 + n0 + b_n4];
    }
    __syncthreads();
#pragma unroll
    for (int k = 0; k < 32; k++) {
      float a[8], bb[4];
      *(float4*)&a[0] = *(const float4*)&As[k][tm * 8];
      *(float4*)&a[4] = *(const float4*)&As[k][tm * 8 + 4];
      *(float4*)&bb[0] = *(const float4*)&Bs[k][tn * 4];
#pragma unroll
      for (int mi = 0; mi < 8; mi++)
#pragma unroll
        for (int ni = 0; ni < 4; ni++) acc[mi][ni] += a[mi] * bb[ni];
    }
    __syncthreads();
  }

  const float4 bs4 = *(const float4*)&bias[n0 + tn * 4];
#pragma unroll
  for (int mi = 0; mi < 8; mi++) {
    int m = m0 + tm * 8 + mi;
    float4 v = make_float4(acc[mi][0] + bs4.x, acc[mi][1] + bs4.y,
                           acc[mi][2] + bs4.z, acc[mi][3] + bs4.w);
    *(float4*)&Y[(size_t)m * 512 + n0 + tn * 4] = v;
  }
}

// ---------------------------------------------------------------------------
extern "C" void kernel_launch(void* const* d_in, const int* in_sizes, int n_in,
                              void* d_out, int out_size, void* d_ws,
                              size_t ws_size, hipStream_t stream) {
  const float* query  = (const float*)d_in[0];
  const float* key_in = (const float*)d_in[1];
  const float* value  = (const float*)d_in[2];
  const float* Wq = (const float*)d_in[3];
  const float* bq = (const float*)d_in[4];
  const float* Wk = (const float*)d_in[5];
  const float* bk = (const float*)d_in[6];
  const float* Wv = (const float*)d_in[7];
  const float* bv = (const float*)d_in[8];
  const float* Wo = (const float*)d_in[9];
  const float* bo = (const float*)d_in[10];
  float* out = (float*)d_out;

  float* ws = (float*)d_ws;
  const size_t SZ = (size_t)32 * 512 * 2048;  // 33,554,432 floats per tensor
  float* qT = ws;                 // becomes attnT in place
  float* kT = ws + SZ;            // becomes ctxT
  float* vT = ws + 2 * SZ;
  float* mean = ws + 3 * SZ;                       // 65536 floats
  float2* stats = (float2*)(ws + 3 * SZ + 65536);  // 65536 float2
  int* delays = (int*)(ws + 3 * SZ + 65536 + 131072);  // 480 ints

  dim3 gemm_grid(8, 512);

  proj_gemm_T<<<gemm_grid, 256, 0, stream>>>(query, Wq, bq, qT);
  proj_gemm_T<<<gemm_grid, 256, 0, stream>>>(key_in, Wk, bk, kT);
  proj_gemm_T<<<gemm_grid, 256, 0, stream>>>(value, Wv, bv, vT);

  fft_correlate<<<dim3(32, 256), 256, 0, stream>>>(qT, kT);

  colstats_kernel<<<dim3(32, 8), 256, 0, stream>>>(qT, mean, stats);
  topk_kernel<<<32, 256, 0, stream>>>(mean, delays);
  ctx_kernel<<<dim3(32, 16, 8), 256, 0, stream>>>(qT, vT, stats, delays, kT);

  out_gemm<<<gemm_grid, 256, 0, stream>>>(kT, Wo, bo, out);
}

// Round 2
// 1382.129 us; speedup vs baseline: 1.9720x; 1.9720x over previous
//
#include <hip/hip_runtime.h>

#define PI_F 3.14159265358979323846f
#define NFFT 2048
#define LOG2N 11
#define LDK 40  // padded LDS row length in bf16 units (32 data + 8 pad)

typedef __attribute__((ext_vector_type(8))) short bf16x8;
typedef __attribute__((ext_vector_type(4))) float f32x4;

__device__ __forceinline__ unsigned short f2bf_rne(float x) {
  unsigned u = __float_as_uint(x);
  return (unsigned short)((u + 0x7fffu + ((u >> 16) & 1u)) >> 16);
}
__device__ __forceinline__ float bf2f(unsigned short h) {
  return __uint_as_float(((unsigned)h) << 16);
}

// ---------------------------------------------------------------------------
// Weight split+transpose: W[k][n] fp32 -> WThi[n][k], WTlo[n][k] bf16.
// hi = truncation (top 16 bits), lo = RNE(x - hi).  out layout per weight z:
// [hi 512*512][lo 512*512] ushort.
// ---------------------------------------------------------------------------
__global__ __launch_bounds__(256) void wsplit_kernel(
    const float* __restrict__ W0, const float* __restrict__ W1,
    const float* __restrict__ W2, const float* __restrict__ W3,
    unsigned short* __restrict__ out) {
  __shared__ float tile[32][33];
  const float* W = (blockIdx.z == 0) ? W0
                   : (blockIdx.z == 1) ? W1
                   : (blockIdx.z == 2) ? W2 : W3;
  unsigned short* hi = out + (size_t)blockIdx.z * 524288;
  unsigned short* lo = hi + 262144;
  const int k0 = blockIdx.x * 32, n0 = blockIdx.y * 32;
  const int c = threadIdx.x & 31, r = threadIdx.x >> 5;
#pragma unroll
  for (int p = 0; p < 4; p++)
    tile[r + 8 * p][c] = W[(size_t)(k0 + r + 8 * p) * 512 + n0 + c];
  __syncthreads();
#pragma unroll
  for (int p = 0; p < 4; p++) {
    int nn = r + 8 * p;
    float x = tile[c][nn];
    unsigned u = __float_as_uint(x);
    unsigned short h = (unsigned short)(u >> 16);
    float hf = __uint_as_float(u & 0xffff0000u);
    unsigned short l = f2bf_rne(x - hf);
    hi[(size_t)(n0 + nn) * 512 + k0 + c] = h;
    lo[(size_t)(n0 + nn) * 512 + k0 + c] = l;
  }
}

// ---------------------------------------------------------------------------
// Split-bf16 projection GEMM (3-product, ~fp32 accuracy), TRANSPOSED output.
// X:[B*T,512] fp32, WThi/WTlo:[512n][512k] bf16.  YT[b][n][t] fp32.
// D[n][t] per 128x128 tile: A-operand = WT rows(n), B-operand = X rows(t).
// ---------------------------------------------------------------------------
__global__ __launch_bounds__(256) void proj_gemm_split(
    const float* __restrict__ X, const unsigned short* __restrict__ WThi,
    const unsigned short* __restrict__ WTlo, const float* __restrict__ bias,
    float* __restrict__ YT) {
  __shared__ __align__(16) unsigned short Wh[128 * LDK];
  __shared__ __align__(16) unsigned short Wl[128 * LDK];
  __shared__ __align__(16) unsigned short Xh[128 * LDK];
  __shared__ __align__(16) unsigned short Xl[128 * LDK];
  const int tid = threadIdx.x;
  const int n0 = blockIdx.x * 128;
  const int b = blockIdx.y >> 4;
  const int t0 = (blockIdx.y & 15) * 128;
  const int w = tid >> 6, l = tid & 63;
  const int wn = (w & 1) * 64;   // row (n) offset of this wave
  const int wt = (w >> 1) * 64;  // col (t) offset
  const int fr = l & 15;         // frag row-within-16
  const int fk = (l >> 4) * 8;   // frag k offset (bf16 units)

  f32x4 acc[4][4];
#pragma unroll
  for (int i = 0; i < 4; i++)
#pragma unroll
    for (int j = 0; j < 4; j++) acc[i][j] = (f32x4)0.f;

  const int srow = tid >> 1, scol = (tid & 1) * 16;
  const float* Xg = X + ((size_t)(b * 2048 + t0 + srow)) * 512 + scol;
  const unsigned short* Whg = WThi + ((size_t)(n0 + srow)) * 512 + scol;
  const unsigned short* Wlg = WTlo + ((size_t)(n0 + srow)) * 512 + scol;
  unsigned short* XhL = &Xh[srow * LDK + scol];
  unsigned short* XlL = &Xl[srow * LDK + scol];
  unsigned short* WhL = &Wh[srow * LDK + scol];
  unsigned short* WlL = &Wl[srow * LDK + scol];

  for (int k0 = 0; k0 < 512; k0 += 32) {
    float xv[16];
    *(float4*)&xv[0] = *(const float4*)&Xg[k0];
    *(float4*)&xv[4] = *(const float4*)&Xg[k0 + 4];
    *(float4*)&xv[8] = *(const float4*)&Xg[k0 + 8];
    *(float4*)&xv[12] = *(const float4*)&Xg[k0 + 12];
    uint4 wh0 = *(const uint4*)&Whg[k0];
    uint4 wh1 = *(const uint4*)&Whg[k0 + 8];
    uint4 wl0 = *(const uint4*)&Wlg[k0];
    uint4 wl1 = *(const uint4*)&Wlg[k0 + 8];
    union { unsigned short us[16]; uint4 q[2]; } hb, lb;
#pragma unroll
    for (int i = 0; i < 16; i++) {
      unsigned u = __float_as_uint(xv[i]);
      hb.us[i] = (unsigned short)(u >> 16);
      float hf = __uint_as_float(u & 0xffff0000u);
      lb.us[i] = f2bf_rne(xv[i] - hf);
    }
    __syncthreads();
    *(uint4*)&XhL[0] = hb.q[0];
    *(uint4*)&XhL[8] = hb.q[1];
    *(uint4*)&XlL[0] = lb.q[0];
    *(uint4*)&XlL[8] = lb.q[1];
    *(uint4*)&WhL[0] = wh0;
    *(uint4*)&WhL[8] = wh1;
    *(uint4*)&WlL[0] = wl0;
    *(uint4*)&WlL[8] = wl1;
    __syncthreads();
    bf16x8 ah[4], al[4], bh[4], bl[4];
#pragma unroll
    for (int i = 0; i < 4; i++) {
      ah[i] = *(const bf16x8*)&Wh[(wn + 16 * i + fr) * LDK + fk];
      al[i] = *(const bf16x8*)&Wl[(wn + 16 * i + fr) * LDK + fk];
      bh[i] = *(const bf16x8*)&Xh[(wt + 16 * i + fr) * LDK + fk];
      bl[i] = *(const bf16x8*)&Xl[(wt + 16 * i + fr) * LDK + fk];
    }
#pragma unroll
    for (int i = 0; i < 4; i++)
#pragma unroll
      for (int j = 0; j < 4; j++) {
        acc[i][j] = __builtin_amdgcn_mfma_f32_16x16x32_bf16(ah[i], bh[j],
                                                            acc[i][j], 0, 0, 0);
        acc[i][j] = __builtin_amdgcn_mfma_f32_16x16x32_bf16(al[i], bh[j],
                                                            acc[i][j], 0, 0, 0);
        acc[i][j] = __builtin_amdgcn_mfma_f32_16x16x32_bf16(ah[i], bl[j],
                                                            acc[i][j], 0, 0, 0);
      }
  }
  const size_t obase = (size_t)b * 512 * 2048;
#pragma unroll
  for (int i = 0; i < 4; i++) {
#pragma unroll
    for (int r = 0; r < 4; r++) {
      int n = n0 + wn + 16 * i + (l >> 4) * 4 + r;
      float bsc = bias[n];
      size_t row = obase + (size_t)n * 2048 + t0 + wt + (l & 15);
#pragma unroll
      for (int j = 0; j < 4; j++) YT[row + 16 * j] = acc[i][j][r] + bsc;
    }
  }
}

// ---------------------------------------------------------------------------
// Plain-bf16 GEMM for v projection: D[t][d], X fp32 -> bf16 hi on the fly.
// Output bf16 [b][t][d].
// ---------------------------------------------------------------------------
__global__ __launch_bounds__(256) void gemm_bf16_vproj(
    const float* __restrict__ X, const unsigned short* __restrict__ WThi,
    const float* __restrict__ bias, unsigned short* __restrict__ Vbf) {
  __shared__ __align__(16) unsigned short Ws[128 * LDK];
  __shared__ __align__(16) unsigned short Xs[128 * LDK];
  const int tid = threadIdx.x;
  const int n0 = blockIdx.x * 128;  // d range
  const int b = blockIdx.y >> 4;
  const int t0 = (blockIdx.y & 15) * 128;
  const int w = tid >> 6, l = tid & 63;
  const int wr = (w & 1) * 64;   // row (t) offset
  const int wc = (w >> 1) * 64;  // col (d) offset
  const int fr = l & 15, fk = (l >> 4) * 8;

  f32x4 acc[4][4];
#pragma unroll
  for (int i = 0; i < 4; i++)
#pragma unroll
    for (int j = 0; j < 4; j++) acc[i][j] = (f32x4)0.f;

  const int srow = tid >> 1, scol = (tid & 1) * 16;
  const float* Xg = X + ((size_t)(b * 2048 + t0 + srow)) * 512 + scol;
  const unsigned short* Wg = WThi + ((size_t)(n0 + srow)) * 512 + scol;
  unsigned short* XsL = &Xs[srow * LDK + scol];
  unsigned short* WsL = &Ws[srow * LDK + scol];

  for (int k0 = 0; k0 < 512; k0 += 32) {
    float xv[16];
    *(float4*)&xv[0] = *(const float4*)&Xg[k0];
    *(float4*)&xv[4] = *(const float4*)&Xg[k0 + 4];
    *(float4*)&xv[8] = *(const float4*)&Xg[k0 + 8];
    *(float4*)&xv[12] = *(const float4*)&Xg[k0 + 12];
    uint4 w0 = *(const uint4*)&Wg[k0];
    uint4 w1 = *(const uint4*)&Wg[k0 + 8];
    union { unsigned short us[16]; uint4 q[2]; } hb;
#pragma unroll
    for (int i = 0; i < 16; i++) hb.us[i] = f2bf_rne(xv[i]);
    __syncthreads();
    *(uint4*)&XsL[0] = hb.q[0];
    *(uint4*)&XsL[8] = hb.q[1];
    *(uint4*)&WsL[0] = w0;
    *(uint4*)&WsL[8] = w1;
    __syncthreads();
    bf16x8 af[4], bf[4];
#pragma unroll
    for (int i = 0; i < 4; i++) {
      af[i] = *(const bf16x8*)&Xs[(wr + 16 * i + fr) * LDK + fk];
      bf[i] = *(const bf16x8*)&Ws[(wc + 16 * i + fr) * LDK + fk];
    }
#pragma unroll
    for (int i = 0; i < 4; i++)
#pragma unroll
      for (int j = 0; j < 4; j++)
        acc[i][j] = __builtin_amdgcn_mfma_f32_16x16x32_bf16(af[i], bf[j],
                                                            acc[i][j], 0, 0, 0);
  }
  float bj[4];
#pragma unroll
  for (int j = 0; j < 4; j++) bj[j] = bias[n0 + wc + 16 * j + (l & 15)];
#pragma unroll
  for (int i = 0; i < 4; i++) {
#pragma unroll
    for (int r = 0; r < 4; r++) {
      int t = t0 + wr + 16 * i + (l >> 4) * 4 + r;
      unsigned short* vrow = Vbf + ((size_t)(b * 2048 + t)) * 512;
#pragma unroll
      for (int j = 0; j < 4; j++) {
        int d = n0 + wc + 16 * j + (l & 15);
        vrow[d] = f2bf_rne(acc[i][j][r] + bj[j]);
      }
    }
  }
}

// ---------------------------------------------------------------------------
// Plain-bf16 GEMM for output projection: D[t][n], A = ctx bf16 [t][d].
// Y[b*2048+t][n] fp32 (= d_out).
// ---------------------------------------------------------------------------
__global__ __launch_bounds__(256) void gemm_bf16_out(
    const unsigned short* __restrict__ Abf,
    const unsigned short* __restrict__ WThi, const float* __restrict__ bias,
    float* __restrict__ Y) {
  __shared__ __align__(16) unsigned short Ws[128 * LDK];
  __shared__ __align__(16) unsigned short Xs[128 * LDK];
  const int tid = threadIdx.x;
  const int n0 = blockIdx.x * 128;
  const int b = blockIdx.y >> 4;
  const int t0 = (blockIdx.y & 15) * 128;
  const int w = tid >> 6, l = tid & 63;
  const int wr = (w & 1) * 64;   // t offset
  const int wc = (w >> 1) * 64;  // n offset
  const int fr = l & 15, fk = (l >> 4) * 8;

  f32x4 acc[4][4];
#pragma unroll
  for (int i = 0; i < 4; i++)
#pragma unroll
    for (int j = 0; j < 4; j++) acc[i][j] = (f32x4)0.f;

  const int srow = tid >> 1, scol = (tid & 1) * 16;
  const unsigned short* Ag = Abf + ((size_t)(b * 2048 + t0 + srow)) * 512 + scol;
  const unsigned short* Wg = WThi + ((size_t)(n0 + srow)) * 512 + scol;
  unsigned short* XsL = &Xs[srow * LDK + scol];
  unsigned short* WsL = &Ws[srow * LDK + scol];

  for (int k0 = 0; k0 < 512; k0 += 32) {
    uint4 a0 = *(const uint4*)&Ag[k0];
    uint4 a1 = *(const uint4*)&Ag[k0 + 8];
    uint4 w0 = *(const uint4*)&Wg[k0];
    uint4 w1 = *(const uint4*)&Wg[k0 + 8];
    __syncthreads();
    *(uint4*)&XsL[0] = a0;
    *(uint4*)&XsL[8] = a1;
    *(uint4*)&WsL[0] = w0;
    *(uint4*)&WsL[8] = w1;
    __syncthreads();
    bf16x8 af[4], bf[4];
#pragma unroll
    for (int i = 0; i < 4; i++) {
      af[i] = *(const bf16x8*)&Xs[(wr + 16 * i + fr) * LDK + fk];
      bf[i] = *(const bf16x8*)&Ws[(wc + 16 * i + fr) * LDK + fk];
    }
#pragma unroll
    for (int i = 0; i < 4; i++)
#pragma unroll
      for (int j = 0; j < 4; j++)
        acc[i][j] = __builtin_amdgcn_mfma_f32_16x16x32_bf16(af[i], bf[j],
                                                            acc[i][j], 0, 0, 0);
  }
  float bj[4];
#pragma unroll
  for (int j = 0; j < 4; j++) bj[j] = bias[n0 + wc + 16 * j + (l & 15)];
#pragma unroll
  for (int i = 0; i < 4; i++) {
#pragma unroll
    for (int r = 0; r < 4; r++) {
      int t = t0 + wr + 16 * i + (l >> 4) * 4 + r;
      float* yrow = Y + ((size_t)(b * 2048 + t)) * 512;
#pragma unroll
      for (int j = 0; j < 4; j++) {
        int n = n0 + wc + 16 * j + (l & 15);
        yrow[n] = acc[i][j][r] + bj[j];
      }
    }
  }
}

// ---------------------------------------------------------------------------
// FFT correlate: per (b, feature-pair) block. qT,kT: [B,512,2048] fp32.
// attn written IN PLACE over qT rows.
// ---------------------------------------------------------------------------
__device__ inline void fft2048_dif(float2* Z, int tid) {
  for (int s = 0; s < LOG2N; s++) {
    int half = NFFT >> (s + 1);
    float angScale = -PI_F / (float)half;
#pragma unroll
    for (int r = 0; r < 4; r++) {
      int p = tid + (r << 8);
      int j = p & (half - 1);
      int i0 = (p << 1) - j;
      int i1 = i0 + half;
      float2 u = Z[i0], v = Z[i1];
      float sx = u.x + v.x, sy = u.y + v.y;
      float dx = u.x - v.x, dy = u.y - v.y;
      float sn, cs;
      __sincosf(angScale * (float)j, &sn, &cs);
      Z[i0] = make_float2(sx, sy);
      Z[i1] = make_float2(dx * cs - dy * sn, dx * sn + dy * cs);
    }
    __syncthreads();
  }
}

__device__ inline void bitrev2048(float2* Z, int tid) {
#pragma unroll
  for (int r = 0; r < 8; r++) {
    int i = tid + (r << 8);
    int rv = (int)(__brev((unsigned)i) >> 21);
    if (i < rv) {
      float2 a = Z[i];
      Z[i] = Z[rv];
      Z[rv] = a;
    }
  }
  __syncthreads();
}

__global__ __launch_bounds__(256) void fft_correlate(
    float* __restrict__ qT, const float* __restrict__ kT) {
  __shared__ float2 Z[NFFT];
  __shared__ float2 Wb[NFFT];
  const int b = blockIdx.x;
  const int d0 = blockIdx.y * 2;
  const int tid = threadIdx.x;
  const size_t base = ((size_t)b * 512 + d0) * 2048;

#pragma unroll
  for (int r = 0; r < 8; r++) {
    int t = tid + (r << 8);
    Z[t] = make_float2(qT[base + t], qT[base + 2048 + t]);
    Wb[t] = make_float2(kT[base + t], kT[base + 2048 + t]);
  }
  __syncthreads();

  fft2048_dif(Z, tid);
  bitrev2048(Z, tid);
  fft2048_dif(Wb, tid);
  bitrev2048(Wb, tid);

  float2 res[8];
#pragma unroll
  for (int r = 0; r < 8; r++) {
    int f = tid + (r << 8);
    int fn = (NFFT - f) & (NFFT - 1);
    float2 Zf = Z[f], Zn = Z[fn], Wf = Wb[f], Wn = Wb[fn];
    float A1x = Zf.x + Zn.x, A1y = Zf.y - Zn.y;
    float B1x = Wf.x + Wn.x, B1y = Wn.y - Wf.y;
    float A2x = Zf.x - Zn.x, A2y = Zf.y + Zn.y;
    float B2x = Wf.x - Wn.x, B2y = -Wf.y - Wn.y;
    float p1x = A1x * B1x - A1y * B1y;
    float p1y = A1x * B1y + A1y * B1x;
    float p2x = A2x * B2x - A2y * B2y;
    float p2y = A2x * B2y + A2y * B2x;
    float pfx = 0.25f * (p1x - p2y);
    float pfy = 0.25f * (p1y + p2x);
    res[r] = make_float2(pfx, -pfy);
  }
  __syncthreads();
#pragma unroll
  for (int r = 0; r < 8; r++) Z[tid + (r << 8)] = res[r];
  __syncthreads();

  fft2048_dif(Z, tid);
  bitrev2048(Z, tid);

  const float scale = 1.0f / (float)NFFT;
#pragma unroll
  for (int r = 0; r < 8; r++) {
    int t = tid + (r << 8);
    float2 z = Z[t];
    qT[base + t] = z.x * scale;
    qT[base + 2048 + t] = -z.y * scale;
  }
}

// ---------------------------------------------------------------------------
// Column stats over d: mean (for top-k) + online softmax (max, expsum)
// ---------------------------------------------------------------------------
__global__ __launch_bounds__(256) void colstats_kernel(
    const float* __restrict__ attnT, float* __restrict__ mean,
    float2* __restrict__ stats) {
  const int b = blockIdx.x;
  const int t = blockIdx.y * 256 + threadIdx.x;
  const size_t base = (size_t)b * 512 * 2048 + t;
  float sum = 0.f, m = -1e30f, s = 0.f;
  for (int d = 0; d < 512; d++) {
    float a = attnT[base + (size_t)d * 2048];
    sum += a;
    float mn = fmaxf(m, a);
    s = s * __expf(m - mn) + __expf(a - mn);
    m = mn;
  }
  mean[b * 2048 + t] = sum * (1.f / 512.f);
  stats[b * 2048 + t] = make_float2(m, s);
}

// ---------------------------------------------------------------------------
// Top-15 per batch (iterative argmax, lowest-index tie-break)
// ---------------------------------------------------------------------------
__global__ __launch_bounds__(256) void topk_kernel(
    const float* __restrict__ mean, int* __restrict__ delays) {
  __shared__ float vals[2048];
  __shared__ float sv[256];
  __shared__ int si[256];
  const int b = blockIdx.x, tid = threadIdx.x;
#pragma unroll
  for (int r = 0; r < 8; r++)
    vals[tid + (r << 8)] = mean[b * 2048 + tid + (r << 8)];
  __syncthreads();
  for (int k = 0; k < 15; k++) {
    float bv = -1e30f;
    int bi = 1 << 30;
#pragma unroll
    for (int r = 0; r < 8; r++) {
      int i = (r << 8) + tid;
      float v = vals[i];
      if (v > bv || (v == bv && i < bi)) { bv = v; bi = i; }
    }
    sv[tid] = bv;
    si[tid] = bi;
    __syncthreads();
    for (int off = 128; off > 0; off >>= 1) {
      if (tid < off) {
        float v2 = sv[tid + off];
        int i2 = si[tid + off];
        if (v2 > sv[tid] || (v2 == sv[tid] && i2 < si[tid])) {
          sv[tid] = v2;
          si[tid] = i2;
        }
      }
      __syncthreads();
    }
    if (tid == 0) {
      delays[b * 15 + k] = si[0];
      vals[si[0]] = -1e30f;
    }
    __syncthreads();
  }
}

// ---------------------------------------------------------------------------
// Context: ctx[b][t][d] = softmax_d(attn)[d][t] * sum_k v[b][(t-dly_k)%T][d]
// v and ctx in bf16 [b][t][d]; attn read strided (L2-absorbed).
// ---------------------------------------------------------------------------
__global__ __launch_bounds__(256) void ctx_kernel(
    const float* __restrict__ attnT, const unsigned short* __restrict__ vbf,
    const float2* __restrict__ stats, const int* __restrict__ delays,
    unsigned short* __restrict__ ctx) {
  const int b = blockIdx.x;
  const int tb = blockIdx.y * 8;
  const int tid = threadIdx.x;
  __shared__ int dly[15];
  if (tid < 15) dly[tid] = delays[b * 15 + tid];
  __syncthreads();
  const size_t vbase = (size_t)b * 2048 * 512;
  const size_t abase = (size_t)b * 512 * 2048;
#pragma unroll
  for (int half = 0; half < 2; half++) {
    int d = half * 256 + tid;
    for (int tt = 0; tt < 8; tt++) {
      int t = tb + tt;
      float rolled = 0.f;
#pragma unroll
      for (int k = 0; k < 15; k++)
        rolled += bf2f(vbf[vbase + (size_t)((t - dly[k]) & 2047) * 512 + d]);
      float2 st = stats[b * 2048 + t];
      float a = attnT[abase + (size_t)d * 2048 + t];
      float p = __expf(a - st.x) / st.y;
      ctx[vbase + (size_t)t * 512 + d] = f2bf_rne(p * rolled);
    }
  }
}

// ---------------------------------------------------------------------------
extern "C" void kernel_launch(void* const* d_in, const int* in_sizes, int n_in,
                              void* d_out, int out_size, void* d_ws,
                              size_t ws_size, hipStream_t stream) {
  const float* query = (const float*)d_in[0];
  const float* key_in = (const float*)d_in[1];
  const float* value = (const float*)d_in[2];
  const float* Wq = (const float*)d_in[3];
  const float* bq = (const float*)d_in[4];
  const float* Wk = (const float*)d_in[5];
  const float* bk = (const float*)d_in[6];
  const float* Wv = (const float*)d_in[7];
  const float* bv = (const float*)d_in[8];
  const float* Wo = (const float*)d_in[9];
  const float* bo = (const float*)d_in[10];
  float* out = (float*)d_out;

  float* ws = (float*)d_ws;
  const size_t SZ = (size_t)32 * 512 * 2048;  // floats per [B,512,2048] tensor
  float* qT = ws;          // fp32 q -> attn (in place)
  float* kT = ws + SZ;     // fp32 k; REUSED after fft: vbf (first half) + ctx
  unsigned short* vbf = (unsigned short*)(ws + SZ);
  unsigned short* ctxbf = (unsigned short*)(ws + SZ + SZ / 2);
  unsigned short* wbuf = (unsigned short*)(ws + 2 * SZ);  // 2,097,152 ushorts
  float* mean = ws + 2 * SZ + 1048576;                    // 65536
  float2* stats = (float2*)(ws + 2 * SZ + 1048576 + 65536);  // 65536 float2
  int* delays = (int*)(ws + 2 * SZ + 1048576 + 65536 + 131072);

  const unsigned short* wq_hi = wbuf + 0 * 524288;
  const unsigned short* wq_lo = wq_hi + 262144;
  const unsigned short* wk_hi = wbuf + 1 * 524288;
  const unsigned short* wk_lo = wk_hi + 262144;
  const unsigned short* wv_hi = wbuf + 2 * 524288;
  const unsigned short* wo_hi = wbuf + 3 * 524288;

  wsplit_kernel<<<dim3(16, 16, 4), 256, 0, stream>>>(Wq, Wk, Wv, Wo, wbuf);

  proj_gemm_split<<<dim3(4, 512), 256, 0, stream>>>(query, wq_hi, wq_lo, bq, qT);
  proj_gemm_split<<<dim3(4, 512), 256, 0, stream>>>(key_in, wk_hi, wk_lo, bk, kT);

  fft_correlate<<<dim3(32, 256), 256, 0, stream>>>(qT, kT);

  // v projection AFTER fft (vbf aliases kT region)
  gemm_bf16_vproj<<<dim3(4, 512), 256, 0, stream>>>(value, wv_hi, bv, vbf);

  colstats_kernel<<<dim3(32, 8), 256, 0, stream>>>(qT, mean, stats);
  topk_kernel<<<32, 256, 0, stream>>>(mean, delays);
  ctx_kernel<<<dim3(32, 256), 256, 0, stream>>>(qT, vbf, stats, delays, ctxbf);

  gemm_bf16_out<<<dim3(4, 512), 256, 0, stream>>>(ctxbf, wo_hi, bo, out);
}